// Round 5
// baseline (1113.378 us; speedup 1.0000x reference)
//
#include <hip/hip_runtime.h>

// ---------- types & helpers ----------
typedef __bf16 v8bf __attribute__((ext_vector_type(8)));
typedef float  v4f  __attribute__((ext_vector_type(4)));

__device__ __forceinline__ float bf2f(unsigned short h) {
    union { unsigned int u; float f; } x; x.u = ((unsigned int)h) << 16; return x.f;
}
__device__ __forceinline__ unsigned short f2bf(float f) {
    union { float f; unsigned int u; } x; x.f = f;
    unsigned int u = x.u;
    u += 0x7fffu + ((u >> 16) & 1u);           // RNE
    return (unsigned short)(u >> 16);
}
// async global->LDS, 16B per lane. LDS dest must be wave-uniform base + lane*16.
__device__ __forceinline__ void gll16(const void* g, void* l) {
    __builtin_amdgcn_global_load_lds((__attribute__((address_space(1))) void*)g,
                                     (__attribute__((address_space(3))) void*)l,
                                     16, 0, 0);
}

// ---------- fp32 -> bf16 elementwise convert (x) ----------
__global__ __launch_bounds__(256) void cvt_f32_bf16(
    const float* __restrict__ in, unsigned short* __restrict__ out)
{
    size_t i = ((size_t)blockIdx.x * 256 + threadIdx.x) * 4;
    float4 v = *(const float4*)&in[i];
    ushort4 o;
    o.x = f2bf(v.x); o.y = f2bf(v.y); o.z = f2bf(v.z); o.w = f2bf(v.w);
    *(ushort4*)&out[i] = o;
}

// ---------- fp32 -> bf16 transposing convert (weights), 64x64 tiles ----------
__global__ __launch_bounds__(256) void transpose_f32_bf16(
    const float* __restrict__ in, unsigned short* __restrict__ out, int ldIn, int M)
{
    __shared__ unsigned short t[64][68];
    const int c0 = blockIdx.x * 64, r0 = blockIdx.y * 64;
    const int lr = threadIdx.x >> 4;
    const int lc = (threadIdx.x & 15) * 4;
#pragma unroll
    for (int i = 0; i < 4; ++i) {
        int row = lr + i * 16;
        float4 v = *(const float4*)&in[(size_t)(r0 + row) * ldIn + c0 + lc];
        ushort4 o;
        o.x = f2bf(v.x); o.y = f2bf(v.y); o.z = f2bf(v.z); o.w = f2bf(v.w);
        *(ushort4*)&t[row][lc] = o;
    }
    __syncthreads();
#pragma unroll
    for (int i = 0; i < 4; ++i) {
        int orow = lr + i * 16;
        ushort4 v;
        v.x = t[lc + 0][orow]; v.y = t[lc + 1][orow];
        v.z = t[lc + 2][orow]; v.w = t[lc + 3][orow];
        *(ushort4*)&out[(size_t)(c0 + orow) * M + r0 + lc] = v;
    }
}

// ---------- fused transpose: Wqkv (3 chunks) + Wo in one launch, z = chunk ----
__global__ __launch_bounds__(256) void transpose_all(
    const float* __restrict__ Wqkv, const float* __restrict__ Wo,
    unsigned short* __restrict__ WT, unsigned short* __restrict__ WoT)
{
    __shared__ unsigned short t[64][68];
    const int z = blockIdx.z;
    const float* in = (z < 3) ? (Wqkv + z * 4096) : Wo;
    unsigned short* out = (z < 3) ? (WT + (size_t)z * 16777216) : WoT;
    const int ldIn = (z < 3) ? 12288 : 4096;
    const int c0 = blockIdx.x * 64, r0 = blockIdx.y * 64;
    const int lr = threadIdx.x >> 4;
    const int lc = (threadIdx.x & 15) * 4;
#pragma unroll
    for (int i = 0; i < 4; ++i) {
        int row = lr + i * 16;
        float4 v = *(const float4*)&in[(size_t)(r0 + row) * ldIn + c0 + lc];
        ushort4 o;
        o.x = f2bf(v.x); o.y = f2bf(v.y); o.z = f2bf(v.z); o.w = f2bf(v.w);
        *(ushort4*)&t[row][lc] = o;
    }
    __syncthreads();
#pragma unroll
    for (int i = 0; i < 4; ++i) {
        int orow = lr + i * 16;
        ushort4 v;
        v.x = t[lc + 0][orow]; v.y = t[lc + 1][orow];
        v.z = t[lc + 2][orow]; v.w = t[lc + 3][orow];
        *(ushort4*)&out[(size_t)(c0 + orow) * 4096 + r0 + lc] = v;
    }
}

// ---------- 256x256 GEMM, 8-phase schedule (m201-style) ----------
// C[M,N] = A[M,4096] * Bt[N,4096]^T, bf16 in, fp32 acc.  8 waves, BK=64,
// 2dbuf x 2half LDS (128 KiB), counted vmcnt(6) once per K-tile.
// MODE 0: fp32 store (grid 256).  MODE 1: RoPE scatter (grid 256).
// MODE 2: V^T scatter (grid 256).
// MODE 3: merged QKV, N=12288 (grid 768): head-group 0 -> Q=Ov (RoPE,
// postScale), 1 -> K=Ov+16M (RoPE, scale 1), 2 -> V^T=Ov+32M.
template <int MODE>
__global__ __launch_bounds__(512, 2) void gemm256(
    const unsigned short* __restrict__ A, const unsigned short* __restrict__ Bt,
    float* __restrict__ Cf, unsigned short* __restrict__ Ov, float postScale)
{
    constexpr int NT = 64;                        // K / 64
    __shared__ unsigned short lA[4 * 8192];       // [buf][half][128 rows x 64 el]
    __shared__ unsigned short lB[4 * 8192];
    const int tid = threadIdx.x;
    const int wave = tid >> 6, lane = tid & 63;
    const int quad = lane >> 4, l16 = lane & 15;
    const int wr = wave >> 2, wc = wave & 3;

    // bijective XCD swizzle: same-XCD blocks share 2 A-panels (L2-resident)
    const int bid = blockIdx.x;
    int m0, n0;
    if (MODE == 3) {
        const int swz = (bid & 7) * 96 + (bid >> 3);    // nwg = 768
        m0 = (swz / 48) * 256; n0 = (swz % 48) * 256;
    } else {
        const int swz = (bid & 7) * 32 + (bid >> 3);    // nwg = 256
        m0 = (swz >> 4) * 256; n0 = (swz & 15) * 256;
    }

    v4f acc[8][4] = {};

    // ---- staging setup (source pre-swizzled; LDS dest lane-linear) ----
    const int srow = tid >> 3;                          // 0..63
    const int sof  = ((tid & 7) ^ (srow & 7)) << 3;     // swizzled src chunk
    const unsigned short* pA[2][2]; const unsigned short* pB[2][2];
#pragma unroll
    for (int H = 0; H < 2; ++H)
#pragma unroll
        for (int i = 0; i < 2; ++i) {
            pA[H][i] = A  + (size_t)(m0 + H * 128 + i * 64 + srow) * 4096 + sof;
            pB[H][i] = Bt + (size_t)(n0 + H * 128 + i * 64 + srow) * 4096 + sof;
        }
    const int dst0 = tid * 8;

    auto stA = [&](int H, int kt) {
        unsigned short* d = &lA[((kt & 1) * 2 + H) * 8192 + dst0];
        gll16(pA[H][0] + kt * 64, d);
        gll16(pA[H][1] + kt * 64, d + 4096);
    };
    auto stB = [&](int H, int kt) {
        unsigned short* d = &lB[((kt & 1) * 2 + H) * 8192 + dst0];
        gll16(pB[H][0] + kt * 64, d);
        gll16(pB[H][1] + kt * 64, d + 4096);
    };

    // prologue: K-tile 0 (4 halves) + K-tile 1 {B0,B1,A0}; A1(1) staged at t=0.p0
    stB(0, 0); stB(1, 0); stA(0, 0); stA(1, 0);
    stB(0, 1); stB(1, 1); stA(0, 1);
    asm volatile("s_waitcnt vmcnt(6)" ::: "memory");    // K-tile 0 landed
    __builtin_amdgcn_s_barrier();

    const int cko0 = (quad ^ (l16 & 7)) << 3;           // kc=0 chunk
    const int cko1 = ((4 + quad) ^ (l16 & 7)) << 3;     // kc=1 chunk
    const int arow0 = l16 * 64;
    const int brow0 = (wc * 16 + l16) * 64;

#pragma unroll 2
    for (int t = 0; t < NT; ++t) {
        const int c = t & 1;
        const unsigned short* lAc = &lA[(c * 2 + wr) * 8192];
        const unsigned short* lB0 = &lB[(c * 2 + 0) * 8192];
        const unsigned short* lB1 = &lB[(c * 2 + 1) * 8192];
        v8bf a[4][2], b0[2][2], b1[2][2];

        // -------- phase 0: (mh0, nh0)  mi 0-3 x ni 0-1 --------
#pragma unroll
        for (int mi = 0; mi < 4; ++mi) {
            a[mi][0] = *(const v8bf*)&lAc[arow0 + mi * 1024 + cko0];
            a[mi][1] = *(const v8bf*)&lAc[arow0 + mi * 1024 + cko1];
        }
#pragma unroll
        for (int ni = 0; ni < 2; ++ni) {
            b0[ni][0] = *(const v8bf*)&lB0[brow0 + ni * 4096 + cko0];
            b0[ni][1] = *(const v8bf*)&lB0[brow0 + ni * 4096 + cko1];
        }
        if (t + 1 < NT) stA(1, t + 1);
        __builtin_amdgcn_s_barrier();
        __builtin_amdgcn_s_setprio(1);
#pragma unroll
        for (int kc = 0; kc < 2; ++kc)
#pragma unroll
            for (int mi = 0; mi < 4; ++mi)
#pragma unroll
                for (int ni = 0; ni < 2; ++ni)
                    acc[mi][ni] = __builtin_amdgcn_mfma_f32_16x16x32_bf16(
                        a[mi][kc], b0[ni][kc], acc[mi][ni], 0, 0, 0);
        __builtin_amdgcn_s_setprio(0);
        __builtin_amdgcn_s_barrier();

        // -------- phase 1: (mh0, nh1)  mi 0-3 x ni 2-3 --------
#pragma unroll
        for (int ni = 0; ni < 2; ++ni) {
            b1[ni][0] = *(const v8bf*)&lB1[brow0 + ni * 4096 + cko0];
            b1[ni][1] = *(const v8bf*)&lB1[brow0 + ni * 4096 + cko1];
        }
        if (t + 2 < NT) stB(0, t + 2);
        __builtin_amdgcn_s_barrier();
        __builtin_amdgcn_s_setprio(1);
#pragma unroll
        for (int kc = 0; kc < 2; ++kc)
#pragma unroll
            for (int mi = 0; mi < 4; ++mi)
#pragma unroll
                for (int ni = 0; ni < 2; ++ni)
                    acc[mi][2 + ni] = __builtin_amdgcn_mfma_f32_16x16x32_bf16(
                        a[mi][kc], b1[ni][kc], acc[mi][2 + ni], 0, 0, 0);
        __builtin_amdgcn_s_setprio(0);
        __builtin_amdgcn_s_barrier();

        // -------- phase 2: (mh1, nh1)  mi 4-7 x ni 2-3 --------
#pragma unroll
        for (int mi = 0; mi < 4; ++mi) {
            a[mi][0] = *(const v8bf*)&lAc[arow0 + (4 + mi) * 1024 + cko0];
            a[mi][1] = *(const v8bf*)&lAc[arow0 + (4 + mi) * 1024 + cko1];
        }
        if (t + 2 < NT) stB(1, t + 2);
        __builtin_amdgcn_s_barrier();
        __builtin_amdgcn_s_setprio(1);
#pragma unroll
        for (int kc = 0; kc < 2; ++kc)
#pragma unroll
            for (int mi = 0; mi < 4; ++mi)
#pragma unroll
                for (int ni = 0; ni < 2; ++ni)
                    acc[4 + mi][2 + ni] = __builtin_amdgcn_mfma_f32_16x16x32_bf16(
                        a[mi][kc], b1[ni][kc], acc[4 + mi][2 + ni], 0, 0, 0);
        __builtin_amdgcn_s_setprio(0);
        __builtin_amdgcn_s_barrier();

        // -------- phase 3: (mh1, nh0)  mi 4-7 x ni 0-1 (b0 from regs) --------
        if (t + 2 < NT) {
            stA(0, t + 2);
            asm volatile("s_waitcnt vmcnt(6)" ::: "memory");   // K-tile t+1 landed
        } else if (t + 1 < NT) {
            asm volatile("s_waitcnt vmcnt(0)" ::: "memory");
        }
        __builtin_amdgcn_s_barrier();
        __builtin_amdgcn_s_setprio(1);
#pragma unroll
        for (int kc = 0; kc < 2; ++kc)
#pragma unroll
            for (int mi = 0; mi < 4; ++mi)
#pragma unroll
                for (int ni = 0; ni < 2; ++ni)
                    acc[4 + mi][ni] = __builtin_amdgcn_mfma_f32_16x16x32_bf16(
                        a[mi][kc], b0[ni][kc], acc[4 + mi][ni], 0, 0, 0);
        __builtin_amdgcn_s_setprio(0);
        __builtin_amdgcn_s_barrier();
    }

    // ---- epilogue; D layout: row(m) = quad*4 + r, col(n) = l16 ----
    if (MODE == 0) {
#pragma unroll
        for (int mi = 0; mi < 8; ++mi) {
            int gm = m0 + wr * 128 + mi * 16 + quad * 4;
#pragma unroll
            for (int ni = 0; ni < 4; ++ni) {
                int gn = n0 + ni * 64 + wc * 16 + l16;
#pragma unroll
                for (int r = 0; r < 4; ++r)
                    Cf[(size_t)(gm + r) * 4096 + gn] = acc[mi][ni][r];
            }
        }
    } else {
        const int head0g = n0 >> 7;                         // global head of this block
        const int hg = (MODE == 3) ? (head0g >> 5) : (MODE == 2 ? 2 : 0);
        const int headl = head0g & 31;                      // head within [0,32)
        if (hg == 2) {
            // V^T: Vo[bh][d][s], s contiguous -> pack 4 rows as ushort4
            unsigned short* Vo = (MODE == 3) ? Ov + 33554432 : Ov;
#pragma unroll
            for (int mi = 0; mi < 8; ++mi) {
                int gmb = m0 + wr * 128 + mi * 16 + quad * 4;
                int b = gmb >> 11, s0 = gmb & 2047;
#pragma unroll
                for (int ni = 0; ni < 4; ++ni) {
                    int head = headl + (ni >> 1);
                    int d = ((ni & 1) << 6) + wc * 16 + l16;
                    ushort4 o;
                    o.x = f2bf(acc[mi][ni][0]); o.y = f2bf(acc[mi][ni][1]);
                    o.z = f2bf(acc[mi][ni][2]); o.w = f2bf(acc[mi][ni][3]);
                    *(ushort4*)&Vo[(((size_t)(b * 32 + head)) << 18) +
                                   ((size_t)d << 11) + s0] = o;
                }
            }
        } else {
            // RoPE: pairs (d1, d1+64) = (acc[mi][2h], acc[mi][2h+1]) same lane
            unsigned short* Qo = (MODE == 3 && hg == 1) ? Ov + 16777216 : Ov;
            const float scl = (MODE == 3 && hg == 1) ? 1.0f : postScale;
            const int d1 = wc * 16 + l16;                  // 0..63
            const float inv = powf(10000.0f, -(float)d1 * 0.015625f);
#pragma unroll
            for (int mi = 0; mi < 8; ++mi) {
                int gmb = m0 + wr * 128 + mi * 16 + quad * 4;
                int b = gmb >> 11, sb = gmb & 2047;
                float sn[4], cs[4];
#pragma unroll
                for (int r = 0; r < 4; ++r)
                    sincosf((float)(sb + r) * inv, &sn[r], &cs[r]);
#pragma unroll
                for (int hd = 0; hd < 2; ++hd) {
                    size_t hb = ((size_t)(b * 32 + headl + hd)) << 11;
#pragma unroll
                    for (int r = 0; r < 4; ++r) {
                        float x1 = acc[mi][2 * hd][r], x2 = acc[mi][2 * hd + 1][r];
                        size_t adr = (hb + sb + r) << 7;
                        Qo[adr + d1]      = f2bf((x1 * cs[r] - x2 * sn[r]) * scl);
                        Qo[adr + d1 + 64] = f2bf((x2 * cs[r] + x1 * sn[r]) * scl);
                    }
                }
            }
        }
    }
}

// ---------- causal flash attention, 128 q-rows/block, shared K/V frags ----------
// Q,K: [b*32+h][s][128] (Q pre-scaled); Vt: [b*32+h][128][s];
// ctx out: [(b*2048+s)][h*128+d] bf16
// Two 64-row q-groups per block share every staged K/V tile AND every kf/vf
// ds_read: per kv-tile, 8 kf reads feed 16 QK MFMA, 8 vf reads feed 16 PV
// MFMA (2x compute per barrier vs the 64-row version).  Group 0 is dead for
// the last 2 tiles (uniform skip of QK/softmax; PV runs with pf0 = 0).
__global__ __launch_bounds__(256, 3) void attn_kernel(
    const unsigned short* __restrict__ Q, const unsigned short* __restrict__ Kg,
    const unsigned short* __restrict__ Vt, unsigned short* __restrict__ ctx)
{
    __shared__ unsigned short lK[2][32 * 128];
    __shared__ unsigned short lV[2][128 * 32];

    const int qt  = gridDim.x - 1 - blockIdx.x;  // long blocks dispatched first
    const int bh  = blockIdx.y;
    const int tid = threadIdx.x;
    const int wave = tid >> 6, lane = tid & 63;
    const int quad = lane >> 4, l16 = lane & 15;
    const int q0 = qt * 128;
    const size_t base = (size_t)bh << 18;

    auto stage = [&](int kv0, int buf) {
#pragma unroll
        for (int it = 0; it < 2; ++it) {
            int cid = it * 256 + tid;
            int row = cid >> 4, chk = cid & 15;
            gll16(Kg + base + ((size_t)(kv0 + row) << 7) + ((chk ^ (row & 15)) << 3),
                  &lK[buf][cid << 3]);
        }
#pragma unroll
        for (int it = 0; it < 2; ++it) {
            int cid = it * 256 + tid;
            int row = cid >> 2, chk = cid & 3;
            gll16(Vt + base + ((size_t)row << 11) + kv0 + ((chk ^ ((row >> 1) & 3)) << 3),
                  &lV[buf][cid << 3]);
        }
    };

    v8bf qf0[4], qf1[4];
    {
        const unsigned short* qrow =
            Q + base + ((size_t)(q0 + wave * 16 + l16) << 7) + quad * 8;
#pragma unroll
        for (int kc = 0; kc < 4; ++kc) {
            qf0[kc] = *(const v8bf*)(qrow + kc * 32);
            qf1[kc] = *(const v8bf*)(qrow + 8192 + kc * 32);   // +64 rows
        }
    }

    const int qg0 = q0 + wave * 16 + l16;        // group-0 q row
    const int qg1 = qg0 + 64;                    // group-1 q row
    float m0r = -1e30f, l0r = 0.f, m1r = -1e30f, l1r = 0.f;
    v4f Oa0[8] = {}, Oa1[8] = {};
    const float c2 = 1.4426950408889634f;
    const float thr = 4.1589045f;                // 6 / log2(e): P <= 2^6
    const int sbase = ((quad & 1) << 5) + l16;

    const int nkt = 4 * qt + 4;
    stage(0, 0);
    for (int kt = 0; kt < nkt; ++kt) {
        const int cur = kt & 1;
        __syncthreads();
        if (kt + 1 < nkt) stage((kt + 1) * 32, cur ^ 1);

        const unsigned short* K_ = &lK[cur][0];
        const unsigned short* V_ = &lV[cur][0];
        const int kv0 = kt * 32;
        const bool g0live = (kt < nkt - 2);      // rows < q0+64 see kv < q0+64

        // S^T = K Q^T  (kv = kv0 + nt*16 + quad*4 + r, q = l16); kf shared
        v4f sc0[2] = {}, sc1[2] = {};
        __builtin_amdgcn_s_setprio(1);
        if (g0live) {
#pragma unroll
            for (int kc = 0; kc < 4; ++kc)
#pragma unroll
                for (int nt = 0; nt < 2; ++nt) {
                    v8bf kf = *(const v8bf*)&K_[((nt * 16 + l16) << 7) +
                                                ((((kc << 2) + quad) ^ l16) << 3)];
                    sc0[nt] = __builtin_amdgcn_mfma_f32_16x16x32_bf16(kf, qf0[kc], sc0[nt], 0, 0, 0);
                    sc1[nt] = __builtin_amdgcn_mfma_f32_16x16x32_bf16(kf, qf1[kc], sc1[nt], 0, 0, 0);
                }
        } else {
#pragma unroll
            for (int kc = 0; kc < 4; ++kc)
#pragma unroll
                for (int nt = 0; nt < 2; ++nt) {
                    v8bf kf = *(const v8bf*)&K_[((nt * 16 + l16) << 7) +
                                                ((((kc << 2) + quad) ^ l16) << 3)];
                    sc1[nt] = __builtin_amdgcn_mfma_f32_16x16x32_bf16(kf, qf1[kc], sc1[nt], 0, 0, 0);
                }
        }
        __builtin_amdgcn_s_setprio(0);

        union { unsigned int u[4]; v8bf v; } pu0, pu1;

        // ---- group 0: mask, online softmax, pack ----
        if (g0live) {
            if (kt >= nkt - 4) {                 // diagonal region for group 0
#pragma unroll
                for (int nt = 0; nt < 2; ++nt) {
                    int kvb = kv0 + nt * 16 + quad * 4;
#pragma unroll
                    for (int r = 0; r < 4; ++r)
                        if (kvb + r > qg0) sc0[nt][r] = -1e30f;
                }
            }
            float tmax = fmaxf(fmaxf(fmaxf(sc0[0][0], sc0[0][1]), fmaxf(sc0[0][2], sc0[0][3])),
                               fmaxf(fmaxf(sc0[1][0], sc0[1][1]), fmaxf(sc0[1][2], sc0[1][3])));
            tmax = fmaxf(tmax, __shfl_xor(tmax, 16));
            tmax = fmaxf(tmax, __shfl_xor(tmax, 32));
            if (__ballot(tmax > m0r + thr) != 0ull) {
                float mnew = fmaxf(m0r, tmax);
                float alpha = exp2f((m0r - mnew) * c2);
                m0r = mnew;
                l0r *= alpha;
#pragma unroll
                for (int d8 = 0; d8 < 8; ++d8)
#pragma unroll
                    for (int r = 0; r < 4; ++r)
                        Oa0[d8][r] *= alpha;
            }
            const float mc = m0r * c2;
            float rsum = 0.f;
#pragma unroll
            for (int nt = 0; nt < 2; ++nt)
#pragma unroll
                for (int r = 0; r < 4; ++r) {
                    float p = exp2f(fmaf(sc0[nt][r], c2, -mc));
                    sc0[nt][r] = p;
                    rsum += p;
                }
            rsum += __shfl_xor(rsum, 16);
            rsum += __shfl_xor(rsum, 32);
            l0r += rsum;

            unsigned int pk0[2], pk1[2];
#pragma unroll
            for (int h = 0; h < 2; ++h) {
                pk0[h] = (unsigned int)f2bf(sc0[0][2 * h]) |
                         ((unsigned int)f2bf(sc0[0][2 * h + 1]) << 16);
                pk1[h] = (unsigned int)f2bf(sc0[1][2 * h]) |
                         ((unsigned int)f2bf(sc0[1][2 * h + 1]) << 16);
            }
#pragma unroll
            for (int j2 = 0; j2 < 4; ++j2) {
                int src = sbase + ((j2 >> 1) << 4);
                int a = __shfl((int)pk0[j2 & 1], src);
                int b = __shfl((int)pk1[j2 & 1], src);
                pu0.u[j2] = (quad < 2) ? (unsigned int)a : (unsigned int)b;
            }
        } else {
            pu0.u[0] = 0; pu0.u[1] = 0; pu0.u[2] = 0; pu0.u[3] = 0;
        }

        // ---- group 1: mask, online softmax, pack ----
        {
            if (kt >= nkt - 2) {                 // diagonal region for group 1
#pragma unroll
                for (int nt = 0; nt < 2; ++nt) {
                    int kvb = kv0 + nt * 16 + quad * 4;
#pragma unroll
                    for (int r = 0; r < 4; ++r)
                        if (kvb + r > qg1) sc1[nt][r] = -1e30f;
                }
            }
            float tmax = fmaxf(fmaxf(fmaxf(sc1[0][0], sc1[0][1]), fmaxf(sc1[0][2], sc1[0][3])),
                               fmaxf(fmaxf(sc1[1][0], sc1[1][1]), fmaxf(sc1[1][2], sc1[1][3])));
            tmax = fmaxf(tmax, __shfl_xor(tmax, 16));
            tmax = fmaxf(tmax, __shfl_xor(tmax, 32));
            if (__ballot(tmax > m1r + thr) != 0ull) {
                float mnew = fmaxf(m1r, tmax);
                float alpha = exp2f((m1r - mnew) * c2);
                m1r = mnew;
                l1r *= alpha;
#pragma unroll
                for (int d8 = 0; d8 < 8; ++d8)
#pragma unroll
                    for (int r = 0; r < 4; ++r)
                        Oa1[d8][r] *= alpha;
            }
            const float mc = m1r * c2;
            float rsum = 0.f;
#pragma unroll
            for (int nt = 0; nt < 2; ++nt)
#pragma unroll
                for (int r = 0; r < 4; ++r) {
                    float p = exp2f(fmaf(sc1[nt][r], c2, -mc));
                    sc1[nt][r] = p;
                    rsum += p;
                }
            rsum += __shfl_xor(rsum, 16);
            rsum += __shfl_xor(rsum, 32);
            l1r += rsum;

            unsigned int pk0[2], pk1[2];
#pragma unroll
            for (int h = 0; h < 2; ++h) {
                pk0[h] = (unsigned int)f2bf(sc1[0][2 * h]) |
                         ((unsigned int)f2bf(sc1[0][2 * h + 1]) << 16);
                pk1[h] = (unsigned int)f2bf(sc1[1][2 * h]) |
                         ((unsigned int)f2bf(sc1[1][2 * h + 1]) << 16);
            }
#pragma unroll
            for (int j2 = 0; j2 < 4; ++j2) {
                int src = sbase + ((j2 >> 1) << 4);
                int a = __shfl((int)pk0[j2 & 1], src);
                int b = __shfl((int)pk1[j2 & 1], src);
                pu1.u[j2] = (quad < 2) ? (unsigned int)a : (unsigned int)b;
            }
        }
        v8bf pf0 = pu0.v, pf1 = pu1.v;

        // O^T += V^T P^T  (d = dt*16 + quad*4 + r, q = l16); vf shared
        __builtin_amdgcn_s_setprio(1);
#pragma unroll
        for (int dt = 0; dt < 8; ++dt) {
            v8bf vf = *(const v8bf*)&V_[((dt * 16 + l16) << 5) +
                                        ((quad ^ ((l16 >> 1) & 3)) << 3)];
            Oa0[dt] = __builtin_amdgcn_mfma_f32_16x16x32_bf16(vf, pf0, Oa0[dt], 0, 0, 0);
            Oa1[dt] = __builtin_amdgcn_mfma_f32_16x16x32_bf16(vf, pf1, Oa1[dt], 0, 0, 0);
        }
        __builtin_amdgcn_s_setprio(0);
    }

    // epilogue: ctx[(b*2048+q)*4096 + h*128 + d]; q lane-local, d = dt*16+quad*4+r
    const int b = bh >> 5, h = bh & 31;
    const float invl0 = 1.0f / l0r, invl1 = 1.0f / l1r;
    size_t rowb0 = ((size_t)(b * 2048 + qg0) << 12) + ((size_t)h << 7);
    size_t rowb1 = rowb0 + ((size_t)64 << 12);
#pragma unroll
    for (int dt = 0; dt < 8; ++dt) {
        ushort4 o;
        o.x = f2bf(Oa0[dt][0] * invl0);
        o.y = f2bf(Oa0[dt][1] * invl0);
        o.z = f2bf(Oa0[dt][2] * invl0);
        o.w = f2bf(Oa0[dt][3] * invl0);
        *(ushort4*)&ctx[rowb0 + dt * 16 + quad * 4] = o;
        ushort4 p;
        p.x = f2bf(Oa1[dt][0] * invl1);
        p.y = f2bf(Oa1[dt][1] * invl1);
        p.z = f2bf(Oa1[dt][2] * invl1);
        p.w = f2bf(Oa1[dt][3] * invl1);
        *(ushort4*)&ctx[rowb1 + dt * 16 + quad * 4] = p;
    }
}

// ---------- launch ----------
extern "C" void kernel_launch(void* const* d_in, const int* in_sizes, int n_in,
                              void* d_out, int out_size, void* d_ws, size_t ws_size,
                              hipStream_t stream)
{
    const float* x    = (const float*)d_in[0];   // (2,2048,4096) fp32
    const float* Wqkv = (const float*)d_in[1];   // (4096,12288)  fp32
    const float* Wo   = (const float*)d_in[2];   // (4096,4096)   fp32
    float* out = (float*)d_out;                  // (2,2048,4096) fp32

    char* ws = (char*)d_ws;
    const size_t B32 = (size_t)32 * 1024 * 1024;
    unsigned short* B0 = (unsigned short*)(ws);              // xb, later ctx
    unsigned short* B1 = (unsigned short*)(ws + 1 * B32);    // Q (pre-scaled, roped)
    unsigned short* B2 = (unsigned short*)(ws + 2 * B32);    // K (roped)
    unsigned short* B3 = (unsigned short*)(ws + 3 * B32);    // V^T

    const float qscale = 0.08838834764831845f;   // 1/sqrt(128)

    if (ws_size >= (size_t)256 * 1024 * 1024) {
        // merged path: 5 launches.  WT = Wqkv^T (96 MiB), WoT = Wo^T (32 MiB)
        unsigned short* WT  = (unsigned short*)(ws + 4 * B32);
        unsigned short* WoT = (unsigned short*)(ws + 7 * B32);
        // 1. x -> bf16
        cvt_f32_bf16<<<16384, 256, 0, stream>>>(x, B0);
        // 2. all weight transposes in one launch
        transpose_all<<<dim3(64, 64, 4), 256, 0, stream>>>(Wqkv, Wo, WT, WoT);
        // 3. merged QKV GEMM: Q/K roped, V transposed (B1,B2,B3 contiguous)
        gemm256<3><<<768, 512, 0, stream>>>(B0, WT, nullptr, B1, qscale);
        // 4. flash attention -> ctx (B0; xb dead after QKV)
        attn_kernel<<<dim3(16, 64), 256, 0, stream>>>(B1, B2, B3, B0);
        // 5. output projection
        gemm256<0><<<256, 512, 0, stream>>>(B0, WoT, out, nullptr, 1.0f);
    } else {
        // fallback (ws >= 160 MiB): chunked path
        unsigned short* B4 = (unsigned short*)(ws + 4 * B32);
        cvt_f32_bf16<<<16384, 256, 0, stream>>>(x, B0);
        transpose_f32_bf16<<<dim3(64, 64), 256, 0, stream>>>(Wqkv, B4, 12288, 4096);
        gemm256<1><<<256, 512, 0, stream>>>(B0, B4, nullptr, B1, qscale);
        transpose_f32_bf16<<<dim3(64, 64), 256, 0, stream>>>(Wqkv + 4096, B4, 12288, 4096);
        gemm256<1><<<256, 512, 0, stream>>>(B0, B4, nullptr, B2, 1.0f);
        transpose_f32_bf16<<<dim3(64, 64), 256, 0, stream>>>(Wqkv + 8192, B4, 12288, 4096);
        gemm256<2><<<256, 512, 0, stream>>>(B0, B4, nullptr, B3, 1.0f);
        transpose_f32_bf16<<<dim3(64, 64), 256, 0, stream>>>(Wo, B4, 4096, 4096);
        attn_kernel<<<dim3(16, 64), 256, 0, stream>>>(B1, B2, B3, B0);
        gemm256<0><<<256, 512, 0, stream>>>(B0, B4, out, nullptr, 1.0f);
    }
}